// Round 19
// baseline (514.517 us; speedup 1.0000x reference)
//
#include <hip/hip_runtime.h>
#include <cmath>

typedef __bf16 bf16_t;
typedef __bf16 bf16x8 __attribute__((ext_vector_type(8)));
typedef __bf16 bf16x4 __attribute__((ext_vector_type(4)));
typedef float f32x4 __attribute__((ext_vector_type(4)));
typedef unsigned int u32x4 __attribute__((ext_vector_type(4)));

namespace {

constexpr int kS = 2048;
constexpr int kTok = 4096;   // B*S
constexpr int kHid = 1024;
constexpr int kDh = 128;
constexpr float kScale = 0.08838834764831843f;   // 1/sqrt(128)

enum {
  EPI_BF16 = 0,
  EPI_BIAS_GELU_BF16 = 4,
  EPI_MULV = 7,
  EPI_PART = 8,        // bf16 split-K partials at Cv + z*M*N
};

__device__ __forceinline__ void gload16(const void* g, void* l) {
  __builtin_amdgcn_global_load_lds(
      (const __attribute__((address_space(1))) void*)g,
      (__attribute__((address_space(3))) void*)l, 16, 0, 0);
}

__device__ __forceinline__ f32x4 mfma16(bf16x8 a, bf16x8 b, f32x4 c) {
  return __builtin_amdgcn_mfma_f32_16x16x32_bf16(a, b, c, 0, 0, 0);
}

// bijective XCD swizzle (T1)
__device__ __forceinline__ unsigned xcd_swz(unsigned bid, unsigned nwg) {
  if ((nwg & 7u) != 0u) return bid;
  return (bid & 7u) * (nwg >> 3) + (bid >> 3);
}

// ---------- A0 = bf16(concat(x, c)) : [4096, 640] ----------
__global__ __launch_bounds__(256) void build_a0_kernel(
    const float* __restrict__ x, const float* __restrict__ c,
    bf16_t* __restrict__ a0)
{
  int i = blockIdx.x * 256 + threadIdx.x;
  if (i >= kTok * 640) return;
  int t = i / 640;
  int col = i - t * 640;
  float v = (col < 512) ? x[(size_t)t * 512 + col]
                        : c[(size_t)t * 128 + (col - 512)];
  a0[i] = (bf16_t)v;
}

// ---------- W [K,N] f32 -> Wt [N,K] bf16 (LDS-tiled transpose) ----------
__global__ __launch_bounds__(256) void transpose_cast_kernel(
    const float* __restrict__ src, bf16_t* __restrict__ dst, int K, int N)
{
  __shared__ float tile[32][33];
  int n0 = blockIdx.x * 32, k0 = blockIdx.y * 32;
  int tx = threadIdx.x & 31, ty = threadIdx.x >> 5;
#pragma unroll
  for (int ii = 0; ii < 4; ++ii) {
    int r = ty + ii * 8;
    tile[r][tx] = src[(size_t)(k0 + r) * N + (n0 + tx)];
  }
  __syncthreads();
#pragma unroll
  for (int ii = 0; ii < 4; ++ii) {
    int r = ty + ii * 8;
    dst[(size_t)(n0 + r) * K + (k0 + tx)] = (bf16_t)tile[tx][r];
  }
}

// ---------- batched variant: z selects one of 4 sources; dst block = z*N*K ----------
__global__ __launch_bounds__(256) void transpose_cast4_kernel(
    const float* __restrict__ w0, const float* __restrict__ w1,
    const float* __restrict__ w2, const float* __restrict__ w3,
    bf16_t* __restrict__ dst, int K, int N)
{
  __shared__ float tile[32][33];
  int z = blockIdx.z;
  const float* src = (z == 0) ? w0 : (z == 1) ? w1 : (z == 2) ? w2 : w3;
  bf16_t* d = dst + (size_t)z * N * K;
  int n0 = blockIdx.x * 32, k0 = blockIdx.y * 32;
  int tx = threadIdx.x & 31, ty = threadIdx.x >> 5;
#pragma unroll
  for (int ii = 0; ii < 4; ++ii) {
    int r = ty + ii * 8;
    tile[r][tx] = src[(size_t)(k0 + r) * N + (n0 + tx)];
  }
  __syncthreads();
#pragma unroll
  for (int ii = 0; ii < 4; ++ii) {
    int r = ty + ii * 8;
    d[(size_t)(n0 + r) * K + (k0 + tx)] = (bf16_t)tile[tx][r];
  }
}

// ---------- layer-tail batched transpose: Wo + W1 + W2 ----------
__global__ __launch_bounds__(256) void transpose_cast3_kernel(
    const float* __restrict__ Wo_, const float* __restrict__ W1_,
    const float* __restrict__ W2_, bf16_t* __restrict__ WoT,
    bf16_t* __restrict__ W1T, bf16_t* __restrict__ W2T)
{
  __shared__ float tile[32][33];
  int bidx = blockIdx.x;
  const float* src; bf16_t* dst; int K, N, t;
  if (bidx < 1024)       { src = Wo_; dst = WoT; K = 1024; N = 1024; t = bidx; }
  else if (bidx < 5120)  { src = W1_; dst = W1T; K = 1024; N = 4096; t = bidx - 1024; }
  else                   { src = W2_; dst = W2T; K = 4096; N = 1024; t = bidx - 5120; }
  int nx = N >> 5;
  int n0 = (t % nx) * 32, k0 = (t / nx) * 32;
  int tx = threadIdx.x & 31, ty = threadIdx.x >> 5;
#pragma unroll
  for (int ii = 0; ii < 4; ++ii) {
    int r = ty + ii * 8;
    tile[r][tx] = src[(size_t)(k0 + r) * N + (n0 + tx)];
  }
  __syncthreads();
#pragma unroll
  for (int ii = 0; ii < 4; ++ii) {
    int r = ty + ii * 8;
    dst[(size_t)(n0 + r) * K + (k0 + tx)] = (bf16_t)tile[tx][r];
  }
}

// ---------- per-head transpose for K AND V in one launch: z in [0,32) ----------
__global__ __launch_bounds__(256) void head_transpose2_kernel(
    const bf16_t* __restrict__ inK, const bf16_t* __restrict__ inV, int ld,
    bf16_t* __restrict__ outK, bf16_t* __restrict__ outV)
{
  __shared__ bf16_t tile[32][33];
  int zz = blockIdx.z;
  int bh = zz & 15;
  const bf16_t* in = (zz < 16) ? inK : inV;
  bf16_t* out = (zz < 16) ? outK : outV;
  int s0 = blockIdx.x * 32;
  int d0 = blockIdx.y * 32;
  int b = bh >> 3, h = bh & 7;
  int tx = threadIdx.x & 31, ty = threadIdx.x >> 5;
#pragma unroll
  for (int ii = 0; ii < 4; ++ii) {
    int r = ty + ii * 8;
    tile[r][tx] = in[(size_t)(b * kS + s0 + r) * ld + h * kDh + d0 + tx];
  }
  __syncthreads();
#pragma unroll
  for (int ii = 0; ii < 4; ++ii) {
    int r = ty + ii * 8;
    out[((size_t)bh * kDh + d0 + r) * kS + s0 + tx] = tile[tx][r];
  }
}

// ---------- shared LN tail ----------
__device__ __forceinline__ void ln_tail(
    f32x4 r, int tid, const float* __restrict__ s, const float* __restrict__ b,
    bf16_t* __restrict__ orow)
{
  int col = tid * 4;
  float sum = r[0] + r[1] + r[2] + r[3];
  float ssq = r[0]*r[0] + r[1]*r[1] + r[2]*r[2] + r[3]*r[3];
#pragma unroll
  for (int m = 32; m >= 1; m >>= 1) {
    sum += __shfl_xor(sum, m, 64);
    ssq += __shfl_xor(ssq, m, 64);
  }
  __shared__ float red[8];
  int wave = tid >> 6;
  if ((tid & 63) == 0) { red[wave] = sum; red[4 + wave] = ssq; }
  __syncthreads();
  sum = red[0] + red[1] + red[2] + red[3];
  ssq = red[4] + red[5] + red[6] + red[7];
  float mean = sum * (1.0f / kHid);
  float var = ssq * (1.0f / kHid) - mean * mean;
  float rstd = rsqrtf(var + 1e-5f);
#pragma unroll
  for (int j = 0; j < 4; ++j)
    orow[col + j] = (bf16_t)((r[j] - mean) * rstd * s[col + j] + b[col + j]);
}

// ---------- H = P + bias; XN = LN(H) ----------
__global__ __launch_bounds__(256) void bias_ln_kernel(
    const bf16_t* __restrict__ P, const float* __restrict__ bias,
    float* __restrict__ H, const float* __restrict__ s,
    const float* __restrict__ b, bf16_t* __restrict__ out)
{
  const int t = blockIdx.x;
  const int tid = threadIdx.x;
  size_t e = (size_t)t * kHid + tid * 4;
  int col = tid * 4;
  bf16x4 p = *(const bf16x4*)&P[e];
  f32x4 bb = *(const f32x4*)&bias[col];
  f32x4 r;
#pragma unroll
  for (int j = 0; j < 4; ++j) r[j] = (float)p[j] + bb[j];
  *(f32x4*)&H[e] = r;
  ln_tail(r, tid, s, b, out + (size_t)t * kHid);
}

// ---------- H += P; XN = LN(H) ----------
__global__ __launch_bounds__(256) void resid_ln_kernel(
    const bf16_t* __restrict__ P, float* __restrict__ H,
    const float* __restrict__ s, const float* __restrict__ b,
    bf16_t* __restrict__ out)
{
  const int t = blockIdx.x;
  const int tid = threadIdx.x;
  size_t e = (size_t)t * kHid + tid * 4;
  bf16x4 p = *(const bf16x4*)&P[e];
  f32x4 h = *(const f32x4*)&H[e];
  f32x4 r;
#pragma unroll
  for (int j = 0; j < 4; ++j) r[j] = h[j] + (float)p[j];
  *(f32x4*)&H[e] = r;
  ln_tail(r, tid, s, b, out + (size_t)t * kHid);
}

// ---------- fused: H += P0+P1 + b2 (bf16 partials), then LN -> out ----------
__global__ __launch_bounds__(256) void ffn2_reduce_ln_kernel(
    const bf16_t* __restrict__ P, const float* __restrict__ b2,
    float* __restrict__ H, const float* __restrict__ s,
    const float* __restrict__ b, bf16_t* __restrict__ out)
{
  const int t = blockIdx.x;
  const int tid = threadIdx.x;
  size_t e = (size_t)t * kHid + tid * 4;
  int col = tid * 4;
  constexpr size_t MN = (size_t)kTok * kHid;
  bf16x4 p0 = *(const bf16x4*)&P[e];
  bf16x4 p1 = *(const bf16x4*)&P[MN + e];
  f32x4 h = *(const f32x4*)&H[e];
  f32x4 bb = *(const f32x4*)&b2[col];
  f32x4 r;
#pragma unroll
  for (int j = 0; j < 4; ++j)
    r[j] = h[j] + (float)p0[j] + (float)p1[j] + bb[j];
  *(f32x4*)&H[e] = r;
  ln_tail(r, tid, s, b, out + (size_t)t * kHid);
}

// ---------- 128-tile GEMM: counted vmcnt + swizzle + XCD swizzle ----------
template <int TM, int EPI>
__global__ __launch_bounds__(256) void gemm_kernel(
    const bf16_t* __restrict__ A, int lda, const bf16_t* __restrict__ Bt, int ldb,
    void* __restrict__ Cv, int ldc, const float* __restrict__ bias,
    const float* __restrict__ bias2, int M, int N, int kSpan)
{
  constexpr int MR = TM / 32;
  constexpr int ASEG = TM / 8;
  constexpr int TOT = ASEG + 16;
  constexpr int PER_WAVE = TOT / 4;
  __shared__ bf16_t As[2][TM * 64];
  __shared__ bf16_t Bs[2][128 * 64];
  const int tid = threadIdx.x;
  const int lane = tid & 63;
  const int wave = tid >> 6;
  const int wr = (wave >> 1) * (MR * 16);
  const int wc = (wave & 1) * 64;
  const unsigned nwg = gridDim.x * gridDim.y;
  const unsigned bid = xcd_swz(blockIdx.y * gridDim.x + blockIdx.x, nwg);
  const int bm = (bid % gridDim.x) * TM;
  const int bn = (bid / gridDim.x) * 128;
  const int kb = blockIdx.z * kSpan;
  const int r_ld = lane >> 3;
  const int cg = ((lane & 7) ^ r_ld) * 8;           // pre-swizzled source col

  f32x4 acc[MR][4] = {};

  auto stage = [&](int bufi, int t) {
    int k0 = kb + t * 64;
#pragma unroll
    for (int i = 0; i < PER_WAVE; ++i) {
      int seg = wave * PER_WAVE + i;
      if (seg < ASEG) {
        int r = seg * 8 + r_ld;
        gload16(&A[(size_t)(bm + r) * lda + k0 + cg], &As[bufi][seg * 512]);
      } else {
        int s2 = seg - ASEG;
        int r = s2 * 8 + r_ld;
        gload16(&Bt[(size_t)(bn + r) * ldb + k0 + cg], &Bs[bufi][s2 * 512]);
      }
    }
  };
  auto compute = [&](int bufi) {
#pragma unroll
    for (int kk = 0; kk < 64; kk += 32) {
      const int cg0 = (kk >> 3) + (lane >> 4);
      bf16x8 af[MR], bfr[4];
#pragma unroll
      for (int m = 0; m < MR; ++m) {
        int row = wr + m * 16 + (lane & 15);
        af[m] = *(const bf16x8*)&As[bufi][row * 64 + ((cg0 ^ (row & 7)) << 3)];
      }
#pragma unroll
      for (int n = 0; n < 4; ++n) {
        int row = wc + n * 16 + (lane & 15);
        bfr[n] = *(const bf16x8*)&Bs[bufi][row * 64 + ((cg0 ^ (row & 7)) << 3)];
      }
#pragma unroll
      for (int m = 0; m < MR; ++m)
#pragma unroll
        for (int n = 0; n < 4; ++n)
          acc[m][n] = mfma16(af[m], bfr[n], acc[m][n]);
    }
  };

  const int nt = kSpan >> 6;
  stage(0, 0);
  stage(1, 1);
  for (int t = 0; t < nt; ++t) {
    if (t + 1 < nt) {
      if constexpr (PER_WAVE == 8) asm volatile("s_waitcnt vmcnt(8)" ::: "memory");
      else                         asm volatile("s_waitcnt vmcnt(6)" ::: "memory");
    } else {
      asm volatile("s_waitcnt vmcnt(0)" ::: "memory");
    }
    __builtin_amdgcn_s_barrier();
    compute(t & 1);
    __builtin_amdgcn_s_barrier();
    if (t + 2 < nt) stage(t & 1, t + 2);
  }

  const int cr = (lane >> 4) * 4;
  const int cc = lane & 15;
#pragma unroll
  for (int m = 0; m < MR; ++m) {
#pragma unroll
    for (int n = 0; n < 4; ++n) {
#pragma unroll
      for (int j = 0; j < 4; ++j) {
        int gr = bm + wr + m * 16 + cr + j;
        int gc = bn + wc + n * 16 + cc;
        size_t off = (size_t)gr * ldc + gc;
        float v = acc[m][n][j];
        if constexpr (EPI == EPI_BF16) {
          ((bf16_t*)Cv)[off] = (bf16_t)v;
        } else if constexpr (EPI == EPI_BIAS_GELU_BF16) {
          v += bias[gc];
          float u3 = v + 0.044715f * v * v * v;
          float th = tanhf(0.7978845608028654f * u3);
          ((bf16_t*)Cv)[off] = (bf16_t)(0.5f * v * (1.0f + th));
        } else if constexpr (EPI == EPI_PART) {
          ((bf16_t*)Cv)[(size_t)blockIdx.z * M * N + off] = (bf16_t)v;
        } else if constexpr (EPI == EPI_MULV) {
          if (gc < 256) {
            ((float*)Cv)[(size_t)gr * 256 + gc] = v + bias[gc];
          } else {
            float r2 = 0.5f * (v + bias2[gc - 256]);
            float sp = (r2 > 20.0f) ? r2 : log1pf(__expf(r2));
            ((float*)Cv)[(size_t)4096 * 256 + (size_t)gr * 256 + (gc - 256)] = sp + 0.001f;
          }
        }
      }
    }
  }
}

// ---------- 256x256 GEMM, BK=32 (64 KB LDS -> 2 blocks/CU; rect XCD tiling) ----------
// LDS rows are 32 cols (64 B). Read swizzle: physical colgroup = cg0 ^ (row&3);
// source pre-swizzled to match (both-sides involution, rule #21). Per K-tile:
// one vmcnt(0)+barrier at tile top (loads issued a full tile ago), then 2
// phases (m-half each, 16 MFMA), staging A in phase 1 and B in phase 2.
template <int EPI>
__global__ __launch_bounds__(512, 2) void gemm256_kernel(
    const bf16_t* __restrict__ A, int lda, const bf16_t* __restrict__ Bt, int ldb,
    void* __restrict__ Cv, int ldc, const float* __restrict__ bias,
    int M, int N, int kSpan)
{
  __shared__ bf16_t As[2][256 * 32];
  __shared__ bf16_t Bs[2][256 * 32];
  const int tid = threadIdx.x;
  const int lane = tid & 63;
  const int wave = tid >> 6;        // 0..7
  const int wm = wave >> 2;
  const int wn = wave & 3;
  // Rectangular XCD tiling for 16x16 grids (round-17: FETCH 37->25 MB).
  int bm_t, bn_t;
  {
    unsigned bid0 = blockIdx.y * gridDim.x + blockIdx.x;
    if (gridDim.x == 16 && gridDim.y == 16) {
      unsigned c = bid0 & 7u, i = bid0 >> 3;
      bm_t = (int)((c & 3u) * 4u + (i & 3u));
      bn_t = (int)((c >> 2) * 8u + (i >> 2));
    } else {
      unsigned bid = xcd_swz(bid0, gridDim.x * gridDim.y);
      bm_t = (int)(bid % gridDim.x);
      bn_t = (int)(bid / gridDim.x);
    }
  }
  const int bm = bm_t * 256;
  const int bn = bn_t * 256;
  const int kb = blockIdx.z * kSpan;
  const int r_ld = lane >> 2;                       // row within 16-row segment
  const int cgs = ((lane & 3) ^ (r_ld & 3)) * 8;    // pre-swizzled source col
  const int rl15 = lane & 15, rhi = lane >> 4;

  f32x4 acc[8][4] = {};

  // per-wave staging pointers: A segs {2w, 2w+1}, B same (seg = 16 rows x 32 cols)
  const bf16_t* pA0; const bf16_t* pA1;
  const bf16_t* pB0; const bf16_t* pB1;
  const int sg0 = (wave * 2) * 512, sg1 = (wave * 2 + 1) * 512;
  {
    int r0 = (wave * 2) * 16 + r_ld, r1 = (wave * 2 + 1) * 16 + r_ld;
    pA0 = A + (size_t)(bm + r0) * lda + kb + cgs;
    pA1 = A + (size_t)(bm + r1) * lda + kb + cgs;
    pB0 = Bt + (size_t)(bn + r0) * ldb + kb + cgs;
    pB1 = Bt + (size_t)(bn + r1) * ldb + kb + cgs;
  }
  auto stageA = [&](int bufi) {
    gload16(pA0, &As[bufi][sg0]); gload16(pA1, &As[bufi][sg1]);
  };
  auto stageB = [&](int bufi) {
    gload16(pB0, &Bs[bufi][sg0]); gload16(pB1, &Bs[bufi][sg1]);
  };
  auto advance = [&]() { pA0 += 32; pA1 += 32; pB0 += 32; pB1 += 32; };
  auto lda_frag = [&](int bufi, int mf) -> bf16x8 {
    int row = wm * 128 + mf * 16 + rl15;
    return *(const bf16x8*)&As[bufi][row * 32 + ((rhi ^ (row & 3)) << 3)];
  };
  auto ldb_frag = [&](int bufi, int nf) -> bf16x8 {
    int row = wn * 64 + nf * 16 + rl15;
    return *(const bf16x8*)&Bs[bufi][row * 32 + ((rhi ^ (row & 3)) << 3)];
  };

  const int nt = kSpan >> 5;                        // K-step = 32
  stageA(0); stageB(0);
  advance();

  bf16x8 bk[4], af[4];
  int cb = 0;

  for (int t = 0; t < nt - 1; ++t) {
    const int nb = cb ^ 1;
    // ---- tile top: all tile-t loads landed (issued one full tile ago) ----
    asm volatile("s_waitcnt vmcnt(0)" ::: "memory");
    __builtin_amdgcn_s_barrier();
    // ---- phase 1: mf 0-3 ----
#pragma unroll
    for (int nf = 0; nf < 4; ++nf) bk[nf] = ldb_frag(cb, nf);
#pragma unroll
    for (int mf = 0; mf < 4; ++mf) af[mf] = lda_frag(cb, mf);
    stageA(nb);
    asm volatile("s_waitcnt lgkmcnt(0)" ::: "memory");
    __builtin_amdgcn_sched_barrier(0);
    __builtin_amdgcn_s_setprio(1);
#pragma unroll
    for (int mf = 0; mf < 4; ++mf)
#pragma unroll
      for (int nf = 0; nf < 4; ++nf)
        acc[mf][nf] = mfma16(af[mf], bk[nf], acc[mf][nf]);
    __builtin_amdgcn_s_setprio(0);
    // ---- phase 2: mf 4-7 (reads cb only; nb writes guarded by tile-top barrier) ----
#pragma unroll
    for (int mf = 0; mf < 4; ++mf) af[mf] = lda_frag(cb, 4 + mf);
    stageB(nb);
    asm volatile("s_waitcnt lgkmcnt(0)" ::: "memory");
    __builtin_amdgcn_sched_barrier(0);
    __builtin_amdgcn_s_setprio(1);
#pragma unroll
    for (int mf = 0; mf < 4; ++mf)
#pragma unroll
      for (int nf = 0; nf < 4; ++nf)
        acc[4 + mf][nf] = mfma16(af[mf], bk[nf], acc[4 + mf][nf]);
    __builtin_amdgcn_s_setprio(0);
    advance();
    cb ^= 1;
  }

  // ---- last tile (no staging) ----
  {
    asm volatile("s_waitcnt vmcnt(0)" ::: "memory");
    __builtin_amdgcn_s_barrier();
#pragma unroll
    for (int nf = 0; nf < 4; ++nf) bk[nf] = ldb_frag(cb, nf);
#pragma unroll
    for (int half = 0; half < 2; ++half) {
#pragma unroll
      for (int mf = 0; mf < 4; ++mf) af[mf] = lda_frag(cb, half * 4 + mf);
      asm volatile("s_waitcnt lgkmcnt(0)" ::: "memory");
      __builtin_amdgcn_sched_barrier(0);
#pragma unroll
      for (int mf = 0; mf < 4; ++mf)
#pragma unroll
        for (int nf = 0; nf < 4; ++nf)
          acc[half * 4 + mf][nf] = mfma16(af[mf], bk[nf], acc[half * 4 + mf][nf]);
    }
  }

  const int cr = rhi * 4;
  const int cc = rl15;
#pragma unroll
  for (int mf = 0; mf < 8; ++mf) {
#pragma unroll
    for (int nf = 0; nf < 4; ++nf) {
#pragma unroll
      for (int j = 0; j < 4; ++j) {
        int gr = bm + wm * 128 + mf * 16 + cr + j;
        int gc = bn + wn * 64 + nf * 16 + cc;
        size_t off = (size_t)gr * ldc + gc;
        float v = acc[mf][nf][j];
        if constexpr (EPI == EPI_BF16) {
          ((bf16_t*)Cv)[off] = (bf16_t)v;
        } else if constexpr (EPI == EPI_BIAS_GELU_BF16) {
          v += bias[gc];
          float u3 = v + 0.044715f * v * v * v;
          float th = tanhf(0.7978845608028654f * u3);
          ((bf16_t*)Cv)[off] = (bf16_t)(0.5f * v * (1.0f + th));
        }
      }
    }
  }
}

// ---------- chunkwise retention, pass A ----------
__global__ __launch_bounds__(256) void chunk_state_kernel(
    const bf16_t* __restrict__ KT, const bf16_t* __restrict__ VT,
    bf16_t* __restrict__ U)
{
  __shared__ bf16_t Ka[128][72];
  __shared__ bf16_t Va[128][72];
  const int tid = threadIdx.x, lane = tid & 63, wave = tid >> 6;
  const int t = blockIdx.x, bh = blockIdx.y, h = bh & 7;
  const float lg2g = log2f(1.0f - exp2f(-5.0f - (float)h));
#pragma unroll
  for (int it = 0; it < 4; ++it) {
    int u = tid + it * 256;
    int r = u >> 3, cg = (u & 7) * 8;
    size_t g = ((size_t)bh * kDh + r) * kS + t * 64 + cg;
    *(u32x4*)&Va[r][cg] = *(const u32x4*)&VT[g];
    bf16x8 kv = *(const bf16x8*)&KT[g];
    bf16x8 ks;
#pragma unroll
    for (int j = 0; j < 8; ++j)
      ks[j] = (bf16_t)((float)kv[j] * exp2f((float)(63 - (cg + j)) * lg2g));
    *(bf16x8*)&Ka[r][cg] = ks;
  }
  __syncthreads();
  f32x4 acc[2][8] = {};
#pragma unroll
  for (int kk = 0; kk < 64; kk += 32) {
    bf16x8 af[2], bfr[8];
#pragma unroll
    for (int m = 0; m < 2; ++m)
      af[m] = *(const bf16x8*)&Va[wave * 32 + m * 16 + (lane & 15)][kk + (lane >> 4) * 8];
#pragma unroll
    for (int n = 0; n < 8; ++n)
      bfr[n] = *(const bf16x8*)&Ka[n * 16 + (lane & 15)][kk + (lane >> 4) * 8];
#pragma unroll
    for (int m = 0; m < 2; ++m)
#pragma unroll
      for (int n = 0; n < 8; ++n)
        acc[m][n] = mfma16(af[m], bfr[n], acc[m][n]);
  }
  size_t base = ((size_t)bh * 32 + t) * 16384;
#pragma unroll
  for (int m = 0; m < 2; ++m)
#pragma unroll
    for (int n = 0; n < 8; ++n)
#pragma unroll
      for (int j = 0; j < 4; ++j) {
        int dv = wave * 32 + m * 16 + (lane >> 4) * 4 + j;
        int dk = n * 16 + (lane & 15);
        U[base + dv * 128 + dk] = (bf16_t)acc[m][n][j];
      }
}

// ---------- pass B: decayed prefix scan over chunks ----------
__global__ __launch_bounds__(256) void chunk_scan_kernel(
    const bf16_t* __restrict__ U, bf16_t* __restrict__ S)
{
  int e = blockIdx.x * 256 + threadIdx.x;
  int bh = blockIdx.y, h = bh & 7;
  float d64 = exp2f(64.0f * log2f(1.0f - exp2f(-5.0f - (float)h)));
  float s = 0.0f;
  size_t base = (size_t)bh * 32 * 16384 + e;
  for (int t = 0; t < 32; ++t) {
    size_t idx = base + (size_t)t * 16384;
    float u = (float)U[idx];
    S[idx] = (bf16_t)s;
    s = d64 * s + u;
  }
}

// ---------- pass C: O = intra + inter, FUSED per-head GroupNorm + silu-gate ----------
__global__ __launch_bounds__(256) void chunk_out_kernel(
    const bf16_t* __restrict__ QB, const bf16_t* __restrict__ KB, int ldq,
    const bf16_t* __restrict__ VT, const bf16_t* __restrict__ S,
    const float* __restrict__ gns, const float* __restrict__ gnb,
    bf16_t* __restrict__ G)
{
  __shared__ bf16_t Qs[64][136];
  __shared__ bf16_t Ks[64][136];
  __shared__ bf16_t Vs[128][72];
  __shared__ bf16_t Ps[64][72];
  const int tid = threadIdx.x, lane = tid & 63, wave = tid >> 6;
  const int t = blockIdx.x, bh = blockIdx.y;
  const int b = bh >> 3, h = bh & 7;
  const float lg2g = log2f(1.0f - exp2f(-5.0f - (float)h));

#pragma unroll
  for (int it = 0; it < 4; ++it) {
    int u = tid + it * 256;
    int r = u >> 4, cg = (u & 15) * 8;
    size_t g = ((size_t)b * kS + t * 64 + r) * ldq + h * kDh + cg;
    *(u32x4*)&Qs[r][cg] = *(const u32x4*)&QB[g];
    *(u32x4*)&Ks[r][cg] = *(const u32x4*)&KB[g];
    int rv = u >> 3, cv = (u & 7) * 8;
    *(u32x4*)&Vs[rv][cv] = *(const u32x4*)&VT[((size_t)bh * kDh + rv) * kS + t * 64 + cv];
  }
  __syncthreads();

  f32x4 sf[4] = {};
#pragma unroll
  for (int kk = 0; kk < 128; kk += 32) {
    bf16x8 aq = *(const bf16x8*)&Qs[wave * 16 + (lane & 15)][kk + (lane >> 4) * 8];
#pragma unroll
    for (int c2 = 0; c2 < 4; ++c2) {
      bf16x8 bk2 = *(const bf16x8*)&Ks[c2 * 16 + (lane & 15)][kk + (lane >> 4) * 8];
      sf[c2] = mfma16(aq, bk2, sf[c2]);
    }
  }
#pragma unroll
  for (int c2 = 0; c2 < 4; ++c2)
#pragma unroll
    for (int j = 0; j < 4; ++j) {
      int nl = wave * 16 + (lane >> 4) * 4 + j;
      int ml = c2 * 16 + (lane & 15);
      int d = nl - ml;
      float w = (d >= 0) ? kScale * exp2f((float)d * lg2g) : 0.0f;
      Ps[nl][ml] = (bf16_t)(sf[c2][j] * w);
    }
  __syncthreads();

  f32x4 oa[8] = {}, oi[8] = {};
#pragma unroll
  for (int ks = 0; ks < 64; ks += 32) {
    bf16x8 ap = *(const bf16x8*)&Ps[wave * 16 + (lane & 15)][ks + (lane >> 4) * 8];
#pragma unroll
    for (int dt = 0; dt < 8; ++dt) {
      bf16x8 bv = *(const bf16x8*)&Vs[dt * 16 + (lane & 15)][ks + (lane >> 4) * 8];
      oa[dt] = mfma16(ap, bv, oa[dt]);
    }
  }
  size_t sbase = ((size_t)bh * 32 + t) * 16384;
#pragma unroll
  for (int kk = 0; kk < 128; kk += 32) {
    bf16x8 aq = *(const bf16x8*)&Qs[wave * 16 + (lane & 15)][kk + (lane >> 4) * 8];
#pragma unroll
    for (int dt = 0; dt < 8; ++dt) {
      bf16x8 bs = *(const bf16x8*)&S[sbase + (size_t)(dt * 16 + (lane & 15)) * 128 + kk + (lane >> 4) * 8];
      oi[dt] = mfma16(aq, bs, oi[dt]);
    }
  }

  float gf[4];
#pragma unroll
  for (int j = 0; j < 4; ++j) {
    int nl = wave * 16 + (lane >> 4) * 4 + j;
    gf[j] = kScale * exp2f((float)(nl + 1) * lg2g);
  }
#pragma unroll
  for (int dt = 0; dt < 8; ++dt)
#pragma unroll
    for (int j = 0; j < 4; ++j)
      oa[dt][j] = oa[dt][j] + gf[j] * oi[dt][j];

  float sc[8], bb[8];
#pragma unroll
  for (int dt = 0; dt < 8; ++dt) {
    int col = h * kDh + dt * 16 + (lane & 15);
    sc[dt] = gns[col]; bb[dt] = gnb[col];
  }
#pragma unroll
  for (int j = 0; j < 4; ++j) {
    float s = 0.f, q = 0.f;
#pragma unroll
    for (int dt = 0; dt < 8; ++dt) { float v = oa[dt][j]; s += v; q += v * v; }
    s += __shfl_xor(s, 1, 64); q += __shfl_xor(q, 1, 64);
    s += __shfl_xor(s, 2, 64); q += __shfl_xor(q, 2, 64);
    s += __shfl_xor(s, 4, 64); q += __shfl_xor(q, 4, 64);
    s += __shfl_xor(s, 8, 64); q += __shfl_xor(q, 8, 64);
    float mean = s * (1.0f / kDh);
    float var = q * (1.0f / kDh) - mean * mean;
    float rstd = rsqrtf(var + 1e-5f);
    int nl = wave * 16 + (lane >> 4) * 4 + j;
    size_t rowoff = ((size_t)b * kS + t * 64 + nl) * 4096 + h * kDh + (lane & 15);
#pragma unroll
    for (int dt = 0; dt < 8; ++dt) {
      float gv = (float)G[rowoff + dt * 16];
      gv = gv / (1.0f + __expf(-gv));
      G[rowoff + dt * 16] = (bf16_t)(((oa[dt][j] - mean) * rstd * sc[dt] + bb[dt]) * gv);
    }
  }
}

template <int TM>
void launch_gemm(int epi, const bf16_t* A, int lda, const bf16_t* Bt, int ldb,
                 void* C, int ldc, const float* bias, const float* bias2,
                 int M, int N, int K, int ksplit, hipStream_t st)
{
  dim3 g(M / TM, N / 128, ksplit), b(256);
  int kSpan = K / ksplit;
  switch (epi) {
    case EPI_BF16:           gemm_kernel<TM, EPI_BF16><<<g, b, 0, st>>>(A, lda, Bt, ldb, C, ldc, bias, bias2, M, N, kSpan); break;
    case EPI_BIAS_GELU_BF16: gemm_kernel<TM, EPI_BIAS_GELU_BF16><<<g, b, 0, st>>>(A, lda, Bt, ldb, C, ldc, bias, bias2, M, N, kSpan); break;
    case EPI_PART:           gemm_kernel<TM, EPI_PART><<<g, b, 0, st>>>(A, lda, Bt, ldb, C, ldc, bias, bias2, M, N, kSpan); break;
    case EPI_MULV:           gemm_kernel<TM, EPI_MULV><<<g, b, 0, st>>>(A, lda, Bt, ldb, C, ldc, bias, bias2, M, N, kSpan); break;
  }
}

void launch_transpose(const float* src, bf16_t* dst, int K, int N, hipStream_t st) {
  transpose_cast_kernel<<<dim3(N / 32, K / 32), dim3(256), 0, st>>>(src, dst, K, N);
}

}  // namespace

extern "C" void kernel_launch(void* const* d_in, const int* in_sizes, int n_in,
                              void* d_out, int out_size, void* d_ws, size_t ws_size,
                              hipStream_t stream) {
  const float* x     = (const float*)d_in[0];
  const float* c     = (const float*)d_in[1];
  const float* W_in  = (const float*)d_in[2];
  const float* b_in  = (const float*)d_in[3];
  const float* ln1_s = (const float*)d_in[4];
  const float* ln1_b = (const float*)d_in[5];
  const float* Wq    = (const float*)d_in[6];
  const float* Wk    = (const float*)d_in[7];
  const float* Wv    = (const float*)d_in[8];
  const float* Wg    = (const float*)d_in[9];
  const float* Wo    = (const float*)d_in[10];
  const float* gn_s  = (const float*)d_in[11];
  const float* gn_b  = (const float*)d_in[12];
  const float* ln2_s = (const float*)d_in[13];
  const float* ln2_b = (const float*)d_in[14];
  const float* W1    = (const float*)d_in[15];
  const float* b1    = (const float*)d_in[16];
  const float* W2    = (const float*)d_in[17];
  const float* b2    = (const float*)d_in[18];
  const float* lnf_s = (const float*)d_in[19];
  const float* lnf_b = (const float*)d_in[20];
  const float* W_mu  = (const float*)d_in[21];
  const float* b_mu  = (const float*)d_in[22];
  const float* W_lv  = (const float*)d_in[23];
  const float* b_lv  = (const float*)d_in[24];

  // workspace layout (~101 MB); overlays have disjoint live ranges.
  char* p = (char*)d_ws;
  bf16_t* WT   = (bf16_t*)p; p += (size_t)4096 * 1024 * 2;   // 8 MB (KT / W1^T)
  bf16_t* A0   = (bf16_t*)p; p += (size_t)4096 * 640 * 2;    // 5 MB (Wo^T after W_in GEMM)
  float*  H    = (float*) p; p += (size_t)4096 * 1024 * 4;   // 16 MB
  bf16_t* XN   = (bf16_t*)p; p += (size_t)4096 * 1024 * 2;   // 8 MB (also VT)
  bf16_t* QKVG = (bf16_t*)p; p += (size_t)4096 * 4096 * 2;   // 32 MB (also F1)
  bf16_t* Sb   = (bf16_t*)p; p += (size_t)16 * 32 * 16384 * 2;  // 16 MB (S / PART 0..1)
  float*  OF   = (float*) p; p += (size_t)4096 * 1024 * 4;   // 16 MB (U / GP+W2^T)
  bf16_t* F1 = QKVG;
  bf16_t* KT = WT;            // [16][128][2048]
  bf16_t* VT = XN;
  bf16_t* Ub = (bf16_t*)OF;   // [16][32][128][128] (16 MB, dead after chunk_scan)
  bf16_t* PART = Sb;          // [2][4096][1024] bf16 = 16 MB (fits Sb)
  bf16_t* GP  = (bf16_t*)OF;                       // 8 MB: W_in/Wo bf16 partial
  bf16_t* W2T = (bf16_t*)((char*)OF + ((size_t)8 << 20));  // 8 MB: W2^T
  bf16_t* WoT = A0;           // 2 MB (A0 dead after W_in GEMM)

  build_a0_kernel<<<dim3((kTok * 640 + 255) / 256), dim3(256), 0, stream>>>(x, c, A0);
  launch_transpose(W_in, WT, 640, 1024, stream);
  launch_gemm<64>(EPI_BF16, A0, 640, WT, 640, GP, 1024, nullptr, nullptr,
                  4096, 1024, 640, 1, stream);
  bias_ln_kernel<<<dim3(4096), dim3(256), 0, stream>>>(GP, b_in, H, ln1_s, ln1_b, XN);

  for (int l = 0; l < 2; ++l) {
    const size_t wsq = (size_t)l * 1024 * 1024;
    // XN holds ln1(H) for this layer.

    transpose_cast4_kernel<<<dim3(32, 32, 4), dim3(256), 0, stream>>>(
        Wq + wsq, Wk + wsq, Wv + wsq, Wg + wsq, WT, 1024, 1024);
    gemm256_kernel<EPI_BF16><<<dim3(16, 16, 1), dim3(512), 0, stream>>>(
        XN, 1024, WT, 1024, QKVG, 4096, nullptr, 4096, 4096, 1024);

    // --- chunkwise retention (gn+gate fused into pass C) ---
    head_transpose2_kernel<<<dim3(64, 4, 32), dim3(256), 0, stream>>>(
        QKVG + 1024, QKVG + 2048, 4096, KT, VT);
    chunk_state_kernel<<<dim3(32, 16), dim3(256), 0, stream>>>(KT, VT, Ub);
    chunk_scan_kernel<<<dim3(64, 16), dim3(256), 0, stream>>>(Ub, Sb);
    // batched layer-tail weight transposes (dest regions dead by here)
    transpose_cast3_kernel<<<dim3(9216), dim3(256), 0, stream>>>(
        Wo + wsq, W1 + (size_t)l * 1024 * 4096, W2 + (size_t)l * 4096 * 1024,
        WoT, WT, W2T);
    chunk_out_kernel<<<dim3(32, 16), dim3(256), 0, stream>>>(
        QKVG, QKVG + 1024, 4096, VT, Sb,
        gn_s + l * 1024, gn_b + l * 1024, QKVG + 3072);

    // Wo: bf16 out + fused residual + ln2
    launch_gemm<64>(EPI_BF16, QKVG + 3072, 4096, WoT, 1024, GP, 1024, nullptr, nullptr,
                    4096, 1024, 1024, 1, stream);
    resid_ln_kernel<<<dim3(4096), dim3(256), 0, stream>>>(
        GP, H, ln2_s + l * 1024, ln2_b + l * 1024, XN);

    gemm256_kernel<EPI_BIAS_GELU_BF16><<<dim3(16, 16, 1), dim3(512), 0, stream>>>(
        XN, 1024, WT, 1024, F1, 4096, b1 + l * 4096, 4096, 4096, 1024);
    // FFN2: 128-tile split-K x2 with bf16 partials, then fused reduce + next LN
    launch_gemm<128>(EPI_PART, F1, 4096, W2T, 4096, PART, 1024, nullptr, nullptr,
                     4096, 1024, 4096, 2, stream);
    const float* s_next = (l == 0) ? (ln1_s + 1024) : lnf_s;
    const float* b_next = (l == 0) ? (ln1_b + 1024) : lnf_b;
    ffn2_reduce_ln_kernel<<<dim3(4096), dim3(256), 0, stream>>>(
        PART, b2 + l * 1024, H, s_next, b_next, XN);
  }

  // XN = lnf(H) from layer 1's fused reduce.
  transpose_cast4_kernel<<<dim3(8, 32, 2), dim3(256), 0, stream>>>(
      W_mu, W_lv, W_mu, W_lv, WT, 1024, 256);
  launch_gemm<64>(EPI_MULV, XN, 1024, WT, 1024, d_out, 512, b_mu, b_lv,
                  4096, 512, 1024, 1, stream);
}

// Round 20
// 501.865 us; speedup vs baseline: 1.0252x; 1.0252x over previous
//
#include <hip/hip_runtime.h>
#include <cmath>

typedef __bf16 bf16_t;
typedef __bf16 bf16x8 __attribute__((ext_vector_type(8)));
typedef __bf16 bf16x4 __attribute__((ext_vector_type(4)));
typedef float f32x4 __attribute__((ext_vector_type(4)));
typedef unsigned int u32x4 __attribute__((ext_vector_type(4)));

namespace {

constexpr int kS = 2048;
constexpr int kTok = 4096;   // B*S
constexpr int kHid = 1024;
constexpr int kDh = 128;
constexpr float kScale = 0.08838834764831843f;   // 1/sqrt(128)

enum {
  EPI_BF16 = 0,
  EPI_BIAS_GELU_BF16 = 4,
  EPI_MULV = 7,
  EPI_PART = 8,        // bf16 split-K partials at Cv + z*M*N
};

__device__ __forceinline__ void gload16(const void* g, void* l) {
  __builtin_amdgcn_global_load_lds(
      (const __attribute__((address_space(1))) void*)g,
      (__attribute__((address_space(3))) void*)l, 16, 0, 0);
}

__device__ __forceinline__ f32x4 mfma16(bf16x8 a, bf16x8 b, f32x4 c) {
  return __builtin_amdgcn_mfma_f32_16x16x32_bf16(a, b, c, 0, 0, 0);
}

// bijective XCD swizzle (T1)
__device__ __forceinline__ unsigned xcd_swz(unsigned bid, unsigned nwg) {
  if ((nwg & 7u) != 0u) return bid;
  return (bid & 7u) * (nwg >> 3) + (bid >> 3);
}

// ---------- A0 = bf16(concat(x, c)) : [4096, 640] ----------
__global__ __launch_bounds__(256) void build_a0_kernel(
    const float* __restrict__ x, const float* __restrict__ c,
    bf16_t* __restrict__ a0)
{
  int i = blockIdx.x * 256 + threadIdx.x;
  if (i >= kTok * 640) return;
  int t = i / 640;
  int col = i - t * 640;
  float v = (col < 512) ? x[(size_t)t * 512 + col]
                        : c[(size_t)t * 128 + (col - 512)];
  a0[i] = (bf16_t)v;
}

// ---------- W [K,N] f32 -> Wt [N,K] bf16 (LDS-tiled transpose) ----------
__global__ __launch_bounds__(256) void transpose_cast_kernel(
    const float* __restrict__ src, bf16_t* __restrict__ dst, int K, int N)
{
  __shared__ float tile[32][33];
  int n0 = blockIdx.x * 32, k0 = blockIdx.y * 32;
  int tx = threadIdx.x & 31, ty = threadIdx.x >> 5;
#pragma unroll
  for (int ii = 0; ii < 4; ++ii) {
    int r = ty + ii * 8;
    tile[r][tx] = src[(size_t)(k0 + r) * N + (n0 + tx)];
  }
  __syncthreads();
#pragma unroll
  for (int ii = 0; ii < 4; ++ii) {
    int r = ty + ii * 8;
    dst[(size_t)(n0 + r) * K + (k0 + tx)] = (bf16_t)tile[tx][r];
  }
}

// ---------- batched variant: z selects one of 4 sources; dst block = z*N*K ----------
__global__ __launch_bounds__(256) void transpose_cast4_kernel(
    const float* __restrict__ w0, const float* __restrict__ w1,
    const float* __restrict__ w2, const float* __restrict__ w3,
    bf16_t* __restrict__ dst, int K, int N)
{
  __shared__ float tile[32][33];
  int z = blockIdx.z;
  const float* src = (z == 0) ? w0 : (z == 1) ? w1 : (z == 2) ? w2 : w3;
  bf16_t* d = dst + (size_t)z * N * K;
  int n0 = blockIdx.x * 32, k0 = blockIdx.y * 32;
  int tx = threadIdx.x & 31, ty = threadIdx.x >> 5;
#pragma unroll
  for (int ii = 0; ii < 4; ++ii) {
    int r = ty + ii * 8;
    tile[r][tx] = src[(size_t)(k0 + r) * N + (n0 + tx)];
  }
  __syncthreads();
#pragma unroll
  for (int ii = 0; ii < 4; ++ii) {
    int r = ty + ii * 8;
    d[(size_t)(n0 + r) * K + (k0 + tx)] = (bf16_t)tile[tx][r];
  }
}

// ---------- layer-tail batched transpose: Wo + W1 + W2 ----------
__global__ __launch_bounds__(256) void transpose_cast3_kernel(
    const float* __restrict__ Wo_, const float* __restrict__ W1_,
    const float* __restrict__ W2_, bf16_t* __restrict__ WoT,
    bf16_t* __restrict__ W1T, bf16_t* __restrict__ W2T)
{
  __shared__ float tile[32][33];
  int bidx = blockIdx.x;
  const float* src; bf16_t* dst; int K, N, t;
  if (bidx < 1024)       { src = Wo_; dst = WoT; K = 1024; N = 1024; t = bidx; }
  else if (bidx < 5120)  { src = W1_; dst = W1T; K = 1024; N = 4096; t = bidx - 1024; }
  else                   { src = W2_; dst = W2T; K = 4096; N = 1024; t = bidx - 5120; }
  int nx = N >> 5;
  int n0 = (t % nx) * 32, k0 = (t / nx) * 32;
  int tx = threadIdx.x & 31, ty = threadIdx.x >> 5;
#pragma unroll
  for (int ii = 0; ii < 4; ++ii) {
    int r = ty + ii * 8;
    tile[r][tx] = src[(size_t)(k0 + r) * N + (n0 + tx)];
  }
  __syncthreads();
#pragma unroll
  for (int ii = 0; ii < 4; ++ii) {
    int r = ty + ii * 8;
    dst[(size_t)(n0 + r) * K + (k0 + tx)] = (bf16_t)tile[tx][r];
  }
}

// ---------- per-head transpose for K AND V in one launch: z in [0,32) ----------
__global__ __launch_bounds__(256) void head_transpose2_kernel(
    const bf16_t* __restrict__ inK, const bf16_t* __restrict__ inV, int ld,
    bf16_t* __restrict__ outK, bf16_t* __restrict__ outV)
{
  __shared__ bf16_t tile[32][33];
  int zz = blockIdx.z;
  int bh = zz & 15;
  const bf16_t* in = (zz < 16) ? inK : inV;
  bf16_t* out = (zz < 16) ? outK : outV;
  int s0 = blockIdx.x * 32;
  int d0 = blockIdx.y * 32;
  int b = bh >> 3, h = bh & 7;
  int tx = threadIdx.x & 31, ty = threadIdx.x >> 5;
#pragma unroll
  for (int ii = 0; ii < 4; ++ii) {
    int r = ty + ii * 8;
    tile[r][tx] = in[(size_t)(b * kS + s0 + r) * ld + h * kDh + d0 + tx];
  }
  __syncthreads();
#pragma unroll
  for (int ii = 0; ii < 4; ++ii) {
    int r = ty + ii * 8;
    out[((size_t)bh * kDh + d0 + r) * kS + s0 + tx] = tile[tx][r];
  }
}

// ---------- shared LN tail ----------
__device__ __forceinline__ void ln_tail(
    f32x4 r, int tid, const float* __restrict__ s, const float* __restrict__ b,
    bf16_t* __restrict__ orow)
{
  int col = tid * 4;
  float sum = r[0] + r[1] + r[2] + r[3];
  float ssq = r[0]*r[0] + r[1]*r[1] + r[2]*r[2] + r[3]*r[3];
#pragma unroll
  for (int m = 32; m >= 1; m >>= 1) {
    sum += __shfl_xor(sum, m, 64);
    ssq += __shfl_xor(ssq, m, 64);
  }
  __shared__ float red[8];
  int wave = tid >> 6;
  if ((tid & 63) == 0) { red[wave] = sum; red[4 + wave] = ssq; }
  __syncthreads();
  sum = red[0] + red[1] + red[2] + red[3];
  ssq = red[4] + red[5] + red[6] + red[7];
  float mean = sum * (1.0f / kHid);
  float var = ssq * (1.0f / kHid) - mean * mean;
  float rstd = rsqrtf(var + 1e-5f);
#pragma unroll
  for (int j = 0; j < 4; ++j)
    orow[col + j] = (bf16_t)((r[j] - mean) * rstd * s[col + j] + b[col + j]);
}

// ---------- H = P + bias; XN = LN(H) ----------
__global__ __launch_bounds__(256) void bias_ln_kernel(
    const bf16_t* __restrict__ P, const float* __restrict__ bias,
    float* __restrict__ H, const float* __restrict__ s,
    const float* __restrict__ b, bf16_t* __restrict__ out)
{
  const int t = blockIdx.x;
  const int tid = threadIdx.x;
  size_t e = (size_t)t * kHid + tid * 4;
  int col = tid * 4;
  bf16x4 p = *(const bf16x4*)&P[e];
  f32x4 bb = *(const f32x4*)&bias[col];
  f32x4 r;
#pragma unroll
  for (int j = 0; j < 4; ++j) r[j] = (float)p[j] + bb[j];
  *(f32x4*)&H[e] = r;
  ln_tail(r, tid, s, b, out + (size_t)t * kHid);
}

// ---------- H += P; XN = LN(H) ----------
__global__ __launch_bounds__(256) void resid_ln_kernel(
    const bf16_t* __restrict__ P, float* __restrict__ H,
    const float* __restrict__ s, const float* __restrict__ b,
    bf16_t* __restrict__ out)
{
  const int t = blockIdx.x;
  const int tid = threadIdx.x;
  size_t e = (size_t)t * kHid + tid * 4;
  bf16x4 p = *(const bf16x4*)&P[e];
  f32x4 h = *(const f32x4*)&H[e];
  f32x4 r;
#pragma unroll
  for (int j = 0; j < 4; ++j) r[j] = h[j] + (float)p[j];
  *(f32x4*)&H[e] = r;
  ln_tail(r, tid, s, b, out + (size_t)t * kHid);
}

// ---------- fused: H += P0+P1 + b2 (bf16 partials), then LN -> out ----------
__global__ __launch_bounds__(256) void ffn2_reduce_ln_kernel(
    const bf16_t* __restrict__ P, const float* __restrict__ b2,
    float* __restrict__ H, const float* __restrict__ s,
    const float* __restrict__ b, bf16_t* __restrict__ out)
{
  const int t = blockIdx.x;
  const int tid = threadIdx.x;
  size_t e = (size_t)t * kHid + tid * 4;
  int col = tid * 4;
  constexpr size_t MN = (size_t)kTok * kHid;
  bf16x4 p0 = *(const bf16x4*)&P[e];
  bf16x4 p1 = *(const bf16x4*)&P[MN + e];
  f32x4 h = *(const f32x4*)&H[e];
  f32x4 bb = *(const f32x4*)&b2[col];
  f32x4 r;
#pragma unroll
  for (int j = 0; j < 4; ++j)
    r[j] = h[j] + (float)p0[j] + (float)p1[j] + bb[j];
  *(f32x4*)&H[e] = r;
  ln_tail(r, tid, s, b, out + (size_t)t * kHid);
}

// ---------- 128-tile GEMM: counted vmcnt + swizzle + XCD swizzle ----------
template <int TM, int EPI>
__global__ __launch_bounds__(256) void gemm_kernel(
    const bf16_t* __restrict__ A, int lda, const bf16_t* __restrict__ Bt, int ldb,
    void* __restrict__ Cv, int ldc, const float* __restrict__ bias,
    const float* __restrict__ bias2, int M, int N, int kSpan)
{
  constexpr int MR = TM / 32;
  constexpr int ASEG = TM / 8;
  constexpr int TOT = ASEG + 16;
  constexpr int PER_WAVE = TOT / 4;
  __shared__ bf16_t As[2][TM * 64];
  __shared__ bf16_t Bs[2][128 * 64];
  const int tid = threadIdx.x;
  const int lane = tid & 63;
  const int wave = tid >> 6;
  const int wr = (wave >> 1) * (MR * 16);
  const int wc = (wave & 1) * 64;
  const unsigned nwg = gridDim.x * gridDim.y;
  const unsigned bid = xcd_swz(blockIdx.y * gridDim.x + blockIdx.x, nwg);
  const int bm = (bid % gridDim.x) * TM;
  const int bn = (bid / gridDim.x) * 128;
  const int kb = blockIdx.z * kSpan;
  const int r_ld = lane >> 3;
  const int cg = ((lane & 7) ^ r_ld) * 8;           // pre-swizzled source col

  f32x4 acc[MR][4] = {};

  auto stage = [&](int bufi, int t) {
    int k0 = kb + t * 64;
#pragma unroll
    for (int i = 0; i < PER_WAVE; ++i) {
      int seg = wave * PER_WAVE + i;
      if (seg < ASEG) {
        int r = seg * 8 + r_ld;
        gload16(&A[(size_t)(bm + r) * lda + k0 + cg], &As[bufi][seg * 512]);
      } else {
        int s2 = seg - ASEG;
        int r = s2 * 8 + r_ld;
        gload16(&Bt[(size_t)(bn + r) * ldb + k0 + cg], &Bs[bufi][s2 * 512]);
      }
    }
  };
  auto compute = [&](int bufi) {
#pragma unroll
    for (int kk = 0; kk < 64; kk += 32) {
      const int cg0 = (kk >> 3) + (lane >> 4);
      bf16x8 af[MR], bfr[4];
#pragma unroll
      for (int m = 0; m < MR; ++m) {
        int row = wr + m * 16 + (lane & 15);
        af[m] = *(const bf16x8*)&As[bufi][row * 64 + ((cg0 ^ (row & 7)) << 3)];
      }
#pragma unroll
      for (int n = 0; n < 4; ++n) {
        int row = wc + n * 16 + (lane & 15);
        bfr[n] = *(const bf16x8*)&Bs[bufi][row * 64 + ((cg0 ^ (row & 7)) << 3)];
      }
#pragma unroll
      for (int m = 0; m < MR; ++m)
#pragma unroll
        for (int n = 0; n < 4; ++n)
          acc[m][n] = mfma16(af[m], bfr[n], acc[m][n]);
    }
  };

  const int nt = kSpan >> 6;
  stage(0, 0);
  stage(1, 1);
  for (int t = 0; t < nt; ++t) {
    if (t + 1 < nt) {
      if constexpr (PER_WAVE == 8) asm volatile("s_waitcnt vmcnt(8)" ::: "memory");
      else                         asm volatile("s_waitcnt vmcnt(6)" ::: "memory");
    } else {
      asm volatile("s_waitcnt vmcnt(0)" ::: "memory");
    }
    __builtin_amdgcn_s_barrier();
    compute(t & 1);
    __builtin_amdgcn_s_barrier();
    if (t + 2 < nt) stage(t & 1, t + 2);
  }

  const int cr = (lane >> 4) * 4;
  const int cc = lane & 15;
#pragma unroll
  for (int m = 0; m < MR; ++m) {
#pragma unroll
    for (int n = 0; n < 4; ++n) {
#pragma unroll
      for (int j = 0; j < 4; ++j) {
        int gr = bm + wr + m * 16 + cr + j;
        int gc = bn + wc + n * 16 + cc;
        size_t off = (size_t)gr * ldc + gc;
        float v = acc[m][n][j];
        if constexpr (EPI == EPI_BF16) {
          ((bf16_t*)Cv)[off] = (bf16_t)v;
        } else if constexpr (EPI == EPI_BIAS_GELU_BF16) {
          v += bias[gc];
          float u3 = v + 0.044715f * v * v * v;
          float th = tanhf(0.7978845608028654f * u3);
          ((bf16_t*)Cv)[off] = (bf16_t)(0.5f * v * (1.0f + th));
        } else if constexpr (EPI == EPI_PART) {
          ((bf16_t*)Cv)[(size_t)blockIdx.z * M * N + off] = (bf16_t)v;
        } else if constexpr (EPI == EPI_MULV) {
          if (gc < 256) {
            ((float*)Cv)[(size_t)gr * 256 + gc] = v + bias[gc];
          } else {
            float r2 = 0.5f * (v + bias2[gc - 256]);
            float sp = (r2 > 20.0f) ? r2 : log1pf(__expf(r2));
            ((float*)Cv)[(size_t)4096 * 256 + (size_t)gr * 256 + (gc - 256)] = sp + 0.001f;
          }
        }
      }
    }
  }
}

// ---------- 256x256 4-phase GEMM (rect XCD tiling; RACE-FREE waits) ----------
// Phase-1 fragment reads span ALL four staged regions, so the only safe
// counted wait is a single vmcnt(0)+barrier per K-tile (drains loads issued
// one full tile ago - cheap). Phases 2-4 need no waits/barriers: reads hit
// the landed cb buffer; nb writes were guarded by the tile-top barrier.
template <int EPI>
__global__ __launch_bounds__(512, 2) void gemm256_kernel(
    const bf16_t* __restrict__ A, int lda, const bf16_t* __restrict__ Bt, int ldb,
    void* __restrict__ Cv, int ldc, const float* __restrict__ bias,
    int M, int N, int kSpan)
{
  __shared__ bf16_t As[2][256 * 64];
  __shared__ bf16_t Bs[2][256 * 64];
  const int tid = threadIdx.x;
  const int lane = tid & 63;
  const int wave = tid >> 6;        // 0..7
  const int wm = wave >> 2;
  const int wn = wave & 3;
  // Rectangular XCD tiling for 16x16 grids (round-17: FETCH 37->25 MB).
  int bm_t, bn_t;
  {
    unsigned bid0 = blockIdx.y * gridDim.x + blockIdx.x;
    if (gridDim.x == 16 && gridDim.y == 16) {
      unsigned c = bid0 & 7u, i = bid0 >> 3;
      bm_t = (int)((c & 3u) * 4u + (i & 3u));
      bn_t = (int)((c >> 2) * 8u + (i >> 2));
    } else {
      unsigned bid = xcd_swz(bid0, gridDim.x * gridDim.y);
      bm_t = (int)(bid % gridDim.x);
      bn_t = (int)(bid / gridDim.x);
    }
  }
  const int bm = bm_t * 256;
  const int bn = bn_t * 256;
  const int kb = blockIdx.z * kSpan;
  const int r_ld = lane >> 3;
  const int cgs = ((lane & 7) ^ r_ld) * 8;
  const int rl15 = lane & 15, rl7 = lane & 7, rhi = lane >> 4;

  f32x4 acc[8][4] = {};

  const bf16_t* pA0a; const bf16_t* pA0b;
  const bf16_t* pA1a; const bf16_t* pA1b;
  const bf16_t* pB0a; const bf16_t* pB0b;
  const bf16_t* pB1a; const bf16_t* pB1b;
  int sg0a, sg0b, sg1a, sg1b;
  {
    int s0a = 0 * 16 + wave * 2 + 0, s0b = 0 * 16 + wave * 2 + 1;
    int s1a = 1 * 16 + wave * 2 + 0, s1b = 1 * 16 + wave * 2 + 1;
    sg0a = s0a * 512; sg0b = s0b * 512; sg1a = s1a * 512; sg1b = s1b * 512;
    pA0a = A + (size_t)(bm + s0a * 8 + r_ld) * lda + kb + cgs;
    pA0b = A + (size_t)(bm + s0b * 8 + r_ld) * lda + kb + cgs;
    pA1a = A + (size_t)(bm + s1a * 8 + r_ld) * lda + kb + cgs;
    pA1b = A + (size_t)(bm + s1b * 8 + r_ld) * lda + kb + cgs;
    pB0a = Bt + (size_t)(bn + s0a * 8 + r_ld) * ldb + kb + cgs;
    pB0b = Bt + (size_t)(bn + s0b * 8 + r_ld) * ldb + kb + cgs;
    pB1a = Bt + (size_t)(bn + s1a * 8 + r_ld) * ldb + kb + cgs;
    pB1b = Bt + (size_t)(bn + s1b * 8 + r_ld) * ldb + kb + cgs;
  }
  auto stageA0 = [&](int bufi) {
    gload16(pA0a, &As[bufi][sg0a]); gload16(pA0b, &As[bufi][sg0b]);
  };
  auto stageA1 = [&](int bufi) {
    gload16(pA1a, &As[bufi][sg1a]); gload16(pA1b, &As[bufi][sg1b]);
  };
  auto stageB0 = [&](int bufi) {
    gload16(pB0a, &Bs[bufi][sg0a]); gload16(pB0b, &Bs[bufi][sg0b]);
  };
  auto stageB1 = [&](int bufi) {
    gload16(pB1a, &Bs[bufi][sg1a]); gload16(pB1b, &Bs[bufi][sg1b]);
  };
  auto advance = [&]() {
    pA0a += 64; pA0b += 64; pA1a += 64; pA1b += 64;
    pB0a += 64; pB0b += 64; pB1a += 64; pB1b += 64;
  };
  auto lda_frag = [&](int bufi, int mf, int kk) -> bf16x8 {
    int row = wm * 128 + mf * 16 + rl15;
    int cg0 = (kk >> 3) + rhi;
    return *(const bf16x8*)&As[bufi][row * 64 + ((cg0 ^ rl7) << 3)];
  };
  auto ldb_frag = [&](int bufi, int nf, int kk) -> bf16x8 {
    int row = wn * 64 + nf * 16 + rl15;
    int cg0 = (kk >> 3) + rhi;
    return *(const bf16x8*)&Bs[bufi][row * 64 + ((cg0 ^ rl7) << 3)];
  };

  const int nt = kSpan >> 6;
  stageA0(0); stageB0(0); stageB1(0); stageA1(0);
  advance();

  bf16x8 bk0[4], bk1[4], af[4];
  int cb = 0;

  for (int t = 0; t < nt - 1; ++t) {
    const int nb = cb ^ 1;
    // ---- tile top: ALL tile-t loads landed (issued a full tile ago) ----
    asm volatile("s_waitcnt vmcnt(0)" ::: "memory");
    __builtin_amdgcn_s_barrier();
    // ---- phase 1: mf 0-3 x kk0 ----
#pragma unroll
    for (int nf = 0; nf < 4; ++nf) bk0[nf] = ldb_frag(cb, nf, 0);
#pragma unroll
    for (int mf = 0; mf < 4; ++mf) af[mf] = lda_frag(cb, mf, 0);
    stageA0(nb); stageB0(nb);
    asm volatile("s_waitcnt lgkmcnt(0)" ::: "memory");
    __builtin_amdgcn_sched_barrier(0);
    __builtin_amdgcn_s_setprio(1);
#pragma unroll
    for (int mf = 0; mf < 4; ++mf)
#pragma unroll
      for (int nf = 0; nf < 4; ++nf)
        acc[mf][nf] = mfma16(af[mf], bk0[nf], acc[mf][nf]);
    __builtin_amdgcn_s_setprio(0);
    // ---- phase 2: mf 0-3 x kk32 (no wait/barrier needed) ----
#pragma unroll
    for (int nf = 0; nf < 4; ++nf) bk1[nf] = ldb_frag(cb, nf, 32);
#pragma unroll
    for (int mf = 0; mf < 4; ++mf) af[mf] = lda_frag(cb, mf, 32);
    stageB1(nb);
    asm volatile("s_waitcnt lgkmcnt(0)" ::: "memory");
    __builtin_amdgcn_sched_barrier(0);
    __builtin_amdgcn_s_setprio(1);
#pragma unroll
    for (int mf = 0; mf < 4; ++mf)
#pragma unroll
      for (int nf = 0; nf < 4; ++nf)
        acc[mf][nf] = mfma16(af[mf], bk1[nf], acc[mf][nf]);
    __builtin_amdgcn_s_setprio(0);
    // ---- phase 3: mf 4-7 x kk0 ----
#pragma unroll
    for (int mf = 0; mf < 4; ++mf) af[mf] = lda_frag(cb, 4 + mf, 0);
    stageA1(nb);
    asm volatile("s_waitcnt lgkmcnt(0)" ::: "memory");
    __builtin_amdgcn_sched_barrier(0);
    __builtin_amdgcn_s_setprio(1);
#pragma unroll
    for (int mf = 0; mf < 4; ++mf)
#pragma unroll
      for (int nf = 0; nf < 4; ++nf)
        acc[4 + mf][nf] = mfma16(af[mf], bk0[nf], acc[4 + mf][nf]);
    __builtin_amdgcn_s_setprio(0);
    // ---- phase 4: mf 4-7 x kk32 ----
#pragma unroll
    for (int mf = 0; mf < 4; ++mf) af[mf] = lda_frag(cb, 4 + mf, 32);
    asm volatile("s_waitcnt lgkmcnt(0)" ::: "memory");
    __builtin_amdgcn_sched_barrier(0);
    __builtin_amdgcn_s_setprio(1);
#pragma unroll
    for (int mf = 0; mf < 4; ++mf)
#pragma unroll
      for (int nf = 0; nf < 4; ++nf)
        acc[4 + mf][nf] = mfma16(af[mf], bk1[nf], acc[4 + mf][nf]);
    __builtin_amdgcn_s_setprio(0);
    advance();
    cb ^= 1;
  }

  // ---- last tile (no staging) ----
  {
    asm volatile("s_waitcnt vmcnt(0)" ::: "memory");
    __builtin_amdgcn_s_barrier();
#pragma unroll
    for (int nf = 0; nf < 4; ++nf) bk0[nf] = ldb_frag(cb, nf, 0);
#pragma unroll
    for (int nf = 0; nf < 4; ++nf) bk1[nf] = ldb_frag(cb, nf, 32);
#pragma unroll
    for (int half = 0; half < 2; ++half) {
#pragma unroll
      for (int mf = 0; mf < 4; ++mf) af[mf] = lda_frag(cb, half * 4 + mf, 0);
      asm volatile("s_waitcnt lgkmcnt(0)" ::: "memory");
      __builtin_amdgcn_sched_barrier(0);
#pragma unroll
      for (int mf = 0; mf < 4; ++mf)
#pragma unroll
        for (int nf = 0; nf < 4; ++nf)
          acc[half * 4 + mf][nf] = mfma16(af[mf], bk0[nf], acc[half * 4 + mf][nf]);
#pragma unroll
      for (int mf = 0; mf < 4; ++mf) af[mf] = lda_frag(cb, half * 4 + mf, 32);
      asm volatile("s_waitcnt lgkmcnt(0)" ::: "memory");
      __builtin_amdgcn_sched_barrier(0);
#pragma unroll
      for (int mf = 0; mf < 4; ++mf)
#pragma unroll
        for (int nf = 0; nf < 4; ++nf)
          acc[half * 4 + mf][nf] = mfma16(af[mf], bk1[nf], acc[half * 4 + mf][nf]);
    }
  }

  const int cr = rhi * 4;
  const int cc = rl15;
#pragma unroll
  for (int mf = 0; mf < 8; ++mf) {
#pragma unroll
    for (int nf = 0; nf < 4; ++nf) {
#pragma unroll
      for (int j = 0; j < 4; ++j) {
        int gr = bm + wm * 128 + mf * 16 + cr + j;
        int gc = bn + wn * 64 + nf * 16 + cc;
        size_t off = (size_t)gr * ldc + gc;
        float v = acc[mf][nf][j];
        if constexpr (EPI == EPI_BF16) {
          ((bf16_t*)Cv)[off] = (bf16_t)v;
        } else if constexpr (EPI == EPI_BIAS_GELU_BF16) {
          v += bias[gc];
          float u3 = v + 0.044715f * v * v * v;
          float th = tanhf(0.7978845608028654f * u3);
          ((bf16_t*)Cv)[off] = (bf16_t)(0.5f * v * (1.0f + th));
        }
      }
    }
  }
}

// ---------- chunkwise retention, pass A ----------
__global__ __launch_bounds__(256) void chunk_state_kernel(
    const bf16_t* __restrict__ KT, const bf16_t* __restrict__ VT,
    bf16_t* __restrict__ U)
{
  __shared__ bf16_t Ka[128][72];
  __shared__ bf16_t Va[128][72];
  const int tid = threadIdx.x, lane = tid & 63, wave = tid >> 6;
  const int t = blockIdx.x, bh = blockIdx.y, h = bh & 7;
  const float lg2g = log2f(1.0f - exp2f(-5.0f - (float)h));
#pragma unroll
  for (int it = 0; it < 4; ++it) {
    int u = tid + it * 256;
    int r = u >> 3, cg = (u & 7) * 8;
    size_t g = ((size_t)bh * kDh + r) * kS + t * 64 + cg;
    *(u32x4*)&Va[r][cg] = *(const u32x4*)&VT[g];
    bf16x8 kv = *(const bf16x8*)&KT[g];
    bf16x8 ks;
#pragma unroll
    for (int j = 0; j < 8; ++j)
      ks[j] = (bf16_t)((float)kv[j] * exp2f((float)(63 - (cg + j)) * lg2g));
    *(bf16x8*)&Ka[r][cg] = ks;
  }
  __syncthreads();
  f32x4 acc[2][8] = {};
#pragma unroll
  for (int kk = 0; kk < 64; kk += 32) {
    bf16x8 af[2], bfr[8];
#pragma unroll
    for (int m = 0; m < 2; ++m)
      af[m] = *(const bf16x8*)&Va[wave * 32 + m * 16 + (lane & 15)][kk + (lane >> 4) * 8];
#pragma unroll
    for (int n = 0; n < 8; ++n)
      bfr[n] = *(const bf16x8*)&Ka[n * 16 + (lane & 15)][kk + (lane >> 4) * 8];
#pragma unroll
    for (int m = 0; m < 2; ++m)
#pragma unroll
      for (int n = 0; n < 8; ++n)
        acc[m][n] = mfma16(af[m], bfr[n], acc[m][n]);
  }
  size_t base = ((size_t)bh * 32 + t) * 16384;
#pragma unroll
  for (int m = 0; m < 2; ++m)
#pragma unroll
    for (int n = 0; n < 8; ++n)
#pragma unroll
      for (int j = 0; j < 4; ++j) {
        int dv = wave * 32 + m * 16 + (lane >> 4) * 4 + j;
        int dk = n * 16 + (lane & 15);
        U[base + dv * 128 + dk] = (bf16_t)acc[m][n][j];
      }
}

// ---------- pass B: decayed prefix scan over chunks ----------
__global__ __launch_bounds__(256) void chunk_scan_kernel(
    const bf16_t* __restrict__ U, bf16_t* __restrict__ S)
{
  int e = blockIdx.x * 256 + threadIdx.x;
  int bh = blockIdx.y, h = bh & 7;
  float d64 = exp2f(64.0f * log2f(1.0f - exp2f(-5.0f - (float)h)));
  float s = 0.0f;
  size_t base = (size_t)bh * 32 * 16384 + e;
  for (int t = 0; t < 32; ++t) {
    size_t idx = base + (size_t)t * 16384;
    float u = (float)U[idx];
    S[idx] = (bf16_t)s;
    s = d64 * s + u;
  }
}

// ---------- pass C: O = intra + inter, FUSED per-head GroupNorm + silu-gate ----------
__global__ __launch_bounds__(256) void chunk_out_kernel(
    const bf16_t* __restrict__ QB, const bf16_t* __restrict__ KB, int ldq,
    const bf16_t* __restrict__ VT, const bf16_t* __restrict__ S,
    const float* __restrict__ gns, const float* __restrict__ gnb,
    bf16_t* __restrict__ G)
{
  __shared__ bf16_t Qs[64][136];
  __shared__ bf16_t Ks[64][136];
  __shared__ bf16_t Vs[128][72];
  __shared__ bf16_t Ps[64][72];
  const int tid = threadIdx.x, lane = tid & 63, wave = tid >> 6;
  const int t = blockIdx.x, bh = blockIdx.y;
  const int b = bh >> 3, h = bh & 7;
  const float lg2g = log2f(1.0f - exp2f(-5.0f - (float)h));

#pragma unroll
  for (int it = 0; it < 4; ++it) {
    int u = tid + it * 256;
    int r = u >> 4, cg = (u & 15) * 8;
    size_t g = ((size_t)b * kS + t * 64 + r) * ldq + h * kDh + cg;
    *(u32x4*)&Qs[r][cg] = *(const u32x4*)&QB[g];
    *(u32x4*)&Ks[r][cg] = *(const u32x4*)&KB[g];
    int rv = u >> 3, cv = (u & 7) * 8;
    *(u32x4*)&Vs[rv][cv] = *(const u32x4*)&VT[((size_t)bh * kDh + rv) * kS + t * 64 + cv];
  }
  __syncthreads();

  f32x4 sf[4] = {};
#pragma unroll
  for (int kk = 0; kk < 128; kk += 32) {
    bf16x8 aq = *(const bf16x8*)&Qs[wave * 16 + (lane & 15)][kk + (lane >> 4) * 8];
#pragma unroll
    for (int c2 = 0; c2 < 4; ++c2) {
      bf16x8 bk2 = *(const bf16x8*)&Ks[c2 * 16 + (lane & 15)][kk + (lane >> 4) * 8];
      sf[c2] = mfma16(aq, bk2, sf[c2]);
    }
  }
#pragma unroll
  for (int c2 = 0; c2 < 4; ++c2)
#pragma unroll
    for (int j = 0; j < 4; ++j) {
      int nl = wave * 16 + (lane >> 4) * 4 + j;
      int ml = c2 * 16 + (lane & 15);
      int d = nl - ml;
      float w = (d >= 0) ? kScale * exp2f((float)d * lg2g) : 0.0f;
      Ps[nl][ml] = (bf16_t)(sf[c2][j] * w);
    }
  __syncthreads();

  f32x4 oa[8] = {}, oi[8] = {};
#pragma unroll
  for (int ks = 0; ks < 64; ks += 32) {
    bf16x8 ap = *(const bf16x8*)&Ps[wave * 16 + (lane & 15)][ks + (lane >> 4) * 8];
#pragma unroll
    for (int dt = 0; dt < 8; ++dt) {
      bf16x8 bv = *(const bf16x8*)&Vs[dt * 16 + (lane & 15)][ks + (lane >> 4) * 8];
      oa[dt] = mfma16(ap, bv, oa[dt]);
    }
  }
  size_t sbase = ((size_t)bh * 32 + t) * 16384;
#pragma unroll
  for (int kk = 0; kk < 128; kk += 32) {
    bf16x8 aq = *(const bf16x8*)&Qs[wave * 16 + (lane & 15)][kk + (lane >> 4) * 8];
#pragma unroll
    for (int dt = 0; dt < 8; ++dt) {
      bf16x8 bs = *(const bf16x8*)&S[sbase + (size_t)(dt * 16 + (lane & 15)) * 128 + kk + (lane >> 4) * 8];
      oi[dt] = mfma16(aq, bs, oi[dt]);
    }
  }

  float gf[4];
#pragma unroll
  for (int j = 0; j < 4; ++j) {
    int nl = wave * 16 + (lane >> 4) * 4 + j;
    gf[j] = kScale * exp2f((float)(nl + 1) * lg2g);
  }
#pragma unroll
  for (int dt = 0; dt < 8; ++dt)
#pragma unroll
    for (int j = 0; j < 4; ++j)
      oa[dt][j] = oa[dt][j] + gf[j] * oi[dt][j];

  float sc[8], bb[8];
#pragma unroll
  for (int dt = 0; dt < 8; ++dt) {
    int col = h * kDh + dt * 16 + (lane & 15);
    sc[dt] = gns[col]; bb[dt] = gnb[col];
  }
#pragma unroll
  for (int j = 0; j < 4; ++j) {
    float s = 0.f, q = 0.f;
#pragma unroll
    for (int dt = 0; dt < 8; ++dt) { float v = oa[dt][j]; s += v; q += v * v; }
    s += __shfl_xor(s, 1, 64); q += __shfl_xor(q, 1, 64);
    s += __shfl_xor(s, 2, 64); q += __shfl_xor(q, 2, 64);
    s += __shfl_xor(s, 4, 64); q += __shfl_xor(q, 4, 64);
    s += __shfl_xor(s, 8, 64); q += __shfl_xor(q, 8, 64);
    float mean = s * (1.0f / kDh);
    float var = q * (1.0f / kDh) - mean * mean;
    float rstd = rsqrtf(var + 1e-5f);
    int nl = wave * 16 + (lane >> 4) * 4 + j;
    size_t rowoff = ((size_t)b * kS + t * 64 + nl) * 4096 + h * kDh + (lane & 15);
#pragma unroll
    for (int dt = 0; dt < 8; ++dt) {
      float gv = (float)G[rowoff + dt * 16];
      gv = gv / (1.0f + __expf(-gv));
      G[rowoff + dt * 16] = (bf16_t)(((oa[dt][j] - mean) * rstd * sc[dt] + bb[dt]) * gv);
    }
  }
}

template <int TM>
void launch_gemm(int epi, const bf16_t* A, int lda, const bf16_t* Bt, int ldb,
                 void* C, int ldc, const float* bias, const float* bias2,
                 int M, int N, int K, int ksplit, hipStream_t st)
{
  dim3 g(M / TM, N / 128, ksplit), b(256);
  int kSpan = K / ksplit;
  switch (epi) {
    case EPI_BF16:           gemm_kernel<TM, EPI_BF16><<<g, b, 0, st>>>(A, lda, Bt, ldb, C, ldc, bias, bias2, M, N, kSpan); break;
    case EPI_BIAS_GELU_BF16: gemm_kernel<TM, EPI_BIAS_GELU_BF16><<<g, b, 0, st>>>(A, lda, Bt, ldb, C, ldc, bias, bias2, M, N, kSpan); break;
    case EPI_PART:           gemm_kernel<TM, EPI_PART><<<g, b, 0, st>>>(A, lda, Bt, ldb, C, ldc, bias, bias2, M, N, kSpan); break;
    case EPI_MULV:           gemm_kernel<TM, EPI_MULV><<<g, b, 0, st>>>(A, lda, Bt, ldb, C, ldc, bias, bias2, M, N, kSpan); break;
  }
}

void launch_transpose(const float* src, bf16_t* dst, int K, int N, hipStream_t st) {
  transpose_cast_kernel<<<dim3(N / 32, K / 32), dim3(256), 0, st>>>(src, dst, K, N);
}

}  // namespace

extern "C" void kernel_launch(void* const* d_in, const int* in_sizes, int n_in,
                              void* d_out, int out_size, void* d_ws, size_t ws_size,
                              hipStream_t stream) {
  const float* x     = (const float*)d_in[0];
  const float* c     = (const float*)d_in[1];
  const float* W_in  = (const float*)d_in[2];
  const float* b_in  = (const float*)d_in[3];
  const float* ln1_s = (const float*)d_in[4];
  const float* ln1_b = (const float*)d_in[5];
  const float* Wq    = (const float*)d_in[6];
  const float* Wk    = (const float*)d_in[7];
  const float* Wv    = (const float*)d_in[8];
  const float* Wg    = (const float*)d_in[9];
  const float* Wo    = (const float*)d_in[10];
  const float* gn_s  = (const float*)d_in[11];
  const float* gn_b  = (const float*)d_in[12];
  const float* ln2_s = (const float*)d_in[13];
  const float* ln2_b = (const float*)d_in[14];
  const float* W1    = (const float*)d_in[15];
  const float* b1    = (const float*)d_in[16];
  const float* W2    = (const float*)d_in[17];
  const float* b2    = (const float*)d_in[18];
  const float* lnf_s = (const float*)d_in[19];
  const float* lnf_b = (const float*)d_in[20];
  const float* W_mu  = (const float*)d_in[21];
  const float* b_mu  = (const float*)d_in[22];
  const float* W_lv  = (const float*)d_in[23];
  const float* b_lv  = (const float*)d_in[24];

  // workspace layout (~101 MB); overlays have disjoint live ranges.
  char* p = (char*)d_ws;
  bf16_t* WT   = (bf16_t*)p; p += (size_t)4096 * 1024 * 2;   // 8 MB (KT / W1^T)
  bf16_t* A0   = (bf16_t*)p; p += (size_t)4096 * 640 * 2;    // 5 MB (Wo^T after W_in GEMM)
  float*  H    = (float*) p; p += (size_t)4096 * 1024 * 4;   // 16 MB
  bf16_t* XN   = (bf16_t*)p; p += (size_t)4096 * 1024 * 2;   // 8 MB (also VT)
  bf16_t* QKVG = (bf16_t*)p; p += (size_t)4096 * 4096 * 2;   // 32 MB (also F1)
  bf16_t* Sb   = (bf16_t*)p; p += (size_t)16 * 32 * 16384 * 2;  // 16 MB (S / PART 0..1)
  float*  OF   = (float*) p; p += (size_t)4096 * 1024 * 4;   // 16 MB (U / GP+W2^T)
  bf16_t* F1 = QKVG;
  bf16_t* KT = WT;            // [16][128][2048]
  bf16_t* VT = XN;
  bf16_t* Ub = (bf16_t*)OF;   // [16][32][128][128] (16 MB, dead after chunk_scan)
  bf16_t* PART = Sb;          // [2][4096][1024] bf16 = 16 MB (fits Sb)
  bf16_t* GP  = (bf16_t*)OF;                       // 8 MB: W_in/Wo bf16 partial
  bf16_t* W2T = (bf16_t*)((char*)OF + ((size_t)8 << 20));  // 8 MB: W2^T
  bf16_t* WoT = A0;           // 2 MB (A0 dead after W_in GEMM)

  build_a0_kernel<<<dim3((kTok * 640 + 255) / 256), dim3(256), 0, stream>>>(x, c, A0);
  launch_transpose(W_in, WT, 640, 1024, stream);
  launch_gemm<64>(EPI_BF16, A0, 640, WT, 640, GP, 1024, nullptr, nullptr,
                  4096, 1024, 640, 1, stream);
  bias_ln_kernel<<<dim3(4096), dim3(256), 0, stream>>>(GP, b_in, H, ln1_s, ln1_b, XN);

  for (int l = 0; l < 2; ++l) {
    const size_t wsq = (size_t)l * 1024 * 1024;
    // XN holds ln1(H) for this layer.

    transpose_cast4_kernel<<<dim3(32, 32, 4), dim3(256), 0, stream>>>(
        Wq + wsq, Wk + wsq, Wv + wsq, Wg + wsq, WT, 1024, 1024);
    gemm256_kernel<EPI_BF16><<<dim3(16, 16, 1), dim3(512), 0, stream>>>(
        XN, 1024, WT, 1024, QKVG, 4096, nullptr, 4096, 4096, 1024);

    // --- chunkwise retention (gn+gate fused into pass C) ---
    head_transpose2_kernel<<<dim3(64, 4, 32), dim3(256), 0, stream>>>(
        QKVG + 1024, QKVG + 2048, 4096, KT, VT);
    chunk_state_kernel<<<dim3(32, 16), dim3(256), 0, stream>>>(KT, VT, Ub);
    chunk_scan_kernel<<<dim3(64, 16), dim3(256), 0, stream>>>(Ub, Sb);
    // batched layer-tail weight transposes (dest regions dead by here)
    transpose_cast3_kernel<<<dim3(9216), dim3(256), 0, stream>>>(
        Wo + wsq, W1 + (size_t)l * 1024 * 4096, W2 + (size_t)l * 4096 * 1024,
        WoT, WT, W2T);
    chunk_out_kernel<<<dim3(32, 16), dim3(256), 0, stream>>>(
        QKVG, QKVG + 1024, 4096, VT, Sb,
        gn_s + l * 1024, gn_b + l * 1024, QKVG + 3072);

    // Wo: bf16 out + fused residual + ln2
    launch_gemm<64>(EPI_BF16, QKVG + 3072, 4096, WoT, 1024, GP, 1024, nullptr, nullptr,
                    4096, 1024, 1024, 1, stream);
    resid_ln_kernel<<<dim3(4096), dim3(256), 0, stream>>>(
        GP, H, ln2_s + l * 1024, ln2_b + l * 1024, XN);

    gemm256_kernel<EPI_BIAS_GELU_BF16><<<dim3(16, 16, 1), dim3(512), 0, stream>>>(
        XN, 1024, WT, 1024, F1, 4096, b1 + l * 4096, 4096, 4096, 1024);
    // FFN2: 128-tile split-K x2 with bf16 partials, then fused reduce + next LN
    launch_gemm<128>(EPI_PART, F1, 4096, W2T, 4096, PART, 1024, nullptr, nullptr,
                     4096, 1024, 4096, 2, stream);
    const float* s_next = (l == 0) ? (ln1_s + 1024) : lnf_s;
    const float* b_next = (l == 0) ? (ln1_b + 1024) : lnf_b;
    ffn2_reduce_ln_kernel<<<dim3(4096), dim3(256), 0, stream>>>(
        PART, b2 + l * 1024, H, s_next, b_next, XN);
  }

  // XN = lnf(H) from layer 1's fused reduce.
  transpose_cast4_kernel<<<dim3(8, 32, 2), dim3(256), 0, stream>>>(
      W_mu, W_lv, W_mu, W_lv, WT, 1024, 256);
  launch_gemm<64>(EPI_MULV, XN, 1024, WT, 1024, d_out, 512, b_mu, b_lv,
                  4096, 512, 1024, 1, stream);
}